// Round 2
// baseline (265.870 us; speedup 1.0000x reference)
//
#include <hip/hip_runtime.h>
#include <math.h>

// FastLearnableEMA: y[b,t,c] = cumsum_t(x * w) / max(a^t, 1e-8)
//   a = clamp(sigmoid(logit_alpha), 1e-4, 1-1e-4)      [C]
//   w[t] = a^t * (t==0 ? 1 : (1-a))
// B=32, T=2048, C=512, fp32. Memory-bound (268 MB min HBM traffic).
//
// v3: two stream-ordered kernels, fully vectorized (float4 per lane,
// 1 KB per wave-load — v1/v2's scalar dword loads plateaued at ~2.8 TB/s,
// ~45% of the float4 copy ceiling).
//   K1: partial[b,tb,c] = sum over 32-step t-block of x*w  (4 MB in d_ws)
//   K2: exclusive prefix from L2-resident partials (<=63 independent
//       float4 loads), re-read x (L3-resident after K1), emit y.
// No __syncthreads, no phase lockstep; stream order is the global barrier.

#define B_    32
#define T_    2048
#define C_    512
#define STEPS 32              // t-steps per partial block
#define NTB   (T_ / STEPS)    // 64 t-blocks
#define C4    (C_ / 4)        // 128 float4 columns
#define ROWS  (B_ * NTB)      // 2048 (b,tb) rows
#define BLK   512
#define RPB   (BLK / C4)      // 4 rows per block
#define GRID  (ROWS / RPB)    // 512 blocks -> 2 blocks/CU, 16 waves/CU

// lanes 0..63 of a wave cover c4 = 0..63 -> 1 KB contiguous per wave-load.

__global__ __launch_bounds__(BLK, 4)
void ema_partial_kernel(const float* __restrict__ x,
                        const float* __restrict__ logit_alpha,
                        float* __restrict__ part) {
    const int tid = threadIdx.x;
    const int c4  = tid & (C4 - 1);
    const int row = blockIdx.x * RPB + (tid >> 7);   // (b,tb) row
    const int b   = row >> 6;                        // NTB == 64
    const int tb  = row & (NTB - 1);
    const int c   = c4 << 2;
    const int t0  = tb * STEPS;

    const float4 lav = *(const float4*)(logit_alpha + c);
    const float la4[4] = {lav.x, lav.y, lav.z, lav.w};

    float a[4], oma[4], ap[4], s[4];
    #pragma unroll
    for (int j = 0; j < 4; ++j) {
        float av = 1.0f / (1.0f + expf(-la4[j]));
        av = fminf(fmaxf(av, 1e-4f), 1.0f - 1e-4f);
        a[j]   = av;
        oma[j] = 1.0f - av;
        ap[j]  = exp2f((float)t0 * log2f(av));  // a^t0 (0 on underflow — those
        s[j]   = 0.0f;                          // weights are <1e-38 anyway)
    }

    const float* __restrict__ xp = x + ((size_t)b * T_ + t0) * C_ + c;
    #pragma unroll 8
    for (int i = 0; i < STEPS; ++i) {
        const float4 v = *(const float4*)(xp + (size_t)i * C_);
        const float xv[4] = {v.x, v.y, v.z, v.w};
        #pragma unroll
        for (int j = 0; j < 4; ++j) {
            const float w = (t0 + i == 0) ? 1.0f : ap[j] * oma[j];
            s[j] = fmaf(xv[j], w, s[j]);
            ap[j] *= a[j];
        }
    }
    *(float4*)(part + (size_t)row * C_ + c) = make_float4(s[0], s[1], s[2], s[3]);
}

__global__ __launch_bounds__(BLK, 4)
void ema_emit_kernel(const float* __restrict__ x,
                     const float* __restrict__ logit_alpha,
                     const float* __restrict__ part,
                     float* __restrict__ y) {
    const int tid = threadIdx.x;
    const int c4  = tid & (C4 - 1);
    const int row = blockIdx.x * RPB + (tid >> 7);
    const int b   = row >> 6;
    const int tb  = row & (NTB - 1);
    const int c   = c4 << 2;
    const int t0  = tb * STEPS;

    // ---- exclusive prefix over earlier t-blocks (independent float4 loads
    // from the 4 MB L2-resident partial array; wave-uniform trip count)
    float S[4] = {0.0f, 0.0f, 0.0f, 0.0f};
    {
        const float* __restrict__ pp = part + (size_t)(b * NTB) * C_ + c;
        for (int tbp = 0; tbp < tb; ++tbp) {
            const float4 v = *(const float4*)(pp + (size_t)tbp * C_);
            S[0] += v.x; S[1] += v.y; S[2] += v.z; S[3] += v.w;
        }
    }

    const float4 lav = *(const float4*)(logit_alpha + c);
    const float la4[4] = {lav.x, lav.y, lav.z, lav.w};

    float a[4], oma[4], ap[4], inva[4], invap[4];
    #pragma unroll
    for (int j = 0; j < 4; ++j) {
        float av = 1.0f / (1.0f + expf(-la4[j]));
        av = fminf(fmaxf(av, 1e-4f), 1.0f - 1e-4f);
        a[j]    = av;
        oma[j]  = 1.0f - av;
        inva[j] = 1.0f / av;
        const float l2a = log2f(av);
        ap[j]    = exp2f((float)t0 * l2a);
        invap[j] = exp2f(-(float)t0 * l2a);  // a^-t0; overflow->inf is clamped
    }                                        // to 1e8 below (matches EPS clamp)

    const float* __restrict__ xp = x + ((size_t)b * T_ + t0) * C_ + c;
    float* __restrict__ yp       = y + ((size_t)b * T_ + t0) * C_ + c;

    #pragma unroll 8
    for (int i = 0; i < STEPS; ++i) {
        const float4 v = *(const float4*)(xp + (size_t)i * C_);
        const float xv[4] = {v.x, v.y, v.z, v.w};
        float out[4];
        #pragma unroll
        for (int j = 0; j < 4; ++j) {
            const float w = (t0 + i == 0) ? 1.0f : ap[j] * oma[j];
            S[j] = fmaf(xv[j], w, S[j]);
            out[j] = S[j] * fminf(invap[j], 1e8f);
            ap[j]    *= a[j];
            invap[j] *= inva[j];
        }
        *(float4*)(yp + (size_t)i * C_) = make_float4(out[0], out[1], out[2], out[3]);
    }
}

extern "C" void kernel_launch(void* const* d_in, const int* in_sizes, int n_in,
                              void* d_out, int out_size, void* d_ws, size_t ws_size,
                              hipStream_t stream) {
    const float* x  = (const float*)d_in[0];   // [32, 2048, 512] fp32
    const float* la = (const float*)d_in[1];   // [512] fp32
    float* y = (float*)d_out;                  // [32, 2048, 512] fp32
    float* part = (float*)d_ws;                // 32*64*512*4 B = 4 MB

    hipLaunchKernelGGL(ema_partial_kernel, dim3(GRID), dim3(BLK), 0, stream,
                       x, la, part);
    hipLaunchKernelGGL(ema_emit_kernel, dim3(GRID), dim3(BLK), 0, stream,
                       x, la, part, y);
}